// Round 2
// baseline (303.598 us; speedup 1.0000x reference)
//
#include <hip/hip_runtime.h>
#include <cstdint>
#include <cstddef>

// ---------------------------------------------------------------------------
// GatedLatticeLayer on MI355X.  B=16 S=512 W=5 H=512 E=256 V=100000.
// MROWS = B*S = 8192.
//
// Round 8: gemmA merged into prep_all (4 launches + 8B memset).
//   - gemmA's operands were fp16 row-copies of raw inputs (no transpose), so
//     its 44 blocks now reg-stage directly from fp32 Wh/Wb/Wm/We/biases
//     (float4x2 load -> cvt -> ds_write_b128), running concurrently with the
//     rest of prep.  Deletes: the gemmA dispatch + gap, the 512 prep blocks
//     that materialized Acat/Whq, and ~4.4 MB intermediate traffic.
//     Bit-identical numerics (same f2h of same fp32, same MFMA order).
//
// Pipeline:
//   prep_all: X->fp16, lmr, weight transposes/copies, bias dots, mask
//             partition, AND gemmA (Breg[M|Wcomb] = Acat @ Whq^T on the fly)
//   gemmB:    y<4: s0, y4-7: hv, y8+: P (group-partitioned rows)
//   attn:     fused gather/scores/softmax/aggregate
//   gemmC:    out = w0*hv + sum_t a_t*bv_t + Ebar @ WvT^T
// GEMM K-loops: BK=32 LDS double-buffer, one barrier per tile.
// ---------------------------------------------------------------------------

typedef unsigned short u16;
typedef _Float16 f16;
typedef __attribute__((ext_vector_type(8))) f16 f16x8;
typedef __attribute__((ext_vector_type(4))) float f32x4;

#define MROWS 8192
#define SS 512

static __device__ __forceinline__ u16 f2h(float x) {
  f16 h = (f16)x;
  return __builtin_bit_cast(u16, h);
}
static __device__ __forceinline__ float h2f(u16 h) {
  return (float)__builtin_bit_cast(f16, h);
}
static __device__ __forceinline__ float sigm(float x) { return 1.f / (1.f + __expf(-x)); }

static __device__ __forceinline__ void gl2lds(const u16* g, u16* l) {
  __builtin_amdgcn_global_load_lds(
      (const __attribute__((address_space(1))) unsigned int*)g,
      (__attribute__((address_space(3))) unsigned int*)l, 16, 0, 0);
}

// ---------------- merged prep: weights + dots + X/lmr + partition + gemmA ---
// [0,64):      WhvT -> Breg rows 512..1023 (fp16)
// [64,160):    WvT (512x768 fp16)
// [160,516):   wave dots: bcat[512+n]=bcomb, u, cb, bcat[0:512) copy
// [516,1028):  X -> fp16 + lmr (+ s0 zero)
// [1028,1060): mask partition -> idx/perm (cnts pre-zeroed via memsetAsync)
// [1060,1104): gemmA: Breg[M rows 0..511; Wcomb rows 1024..1919], staged
//              directly from fp32 inputs (no Acat/Whq intermediates).
__global__ __launch_bounds__(256) void prep_all(
    const float* __restrict__ X, const float* __restrict__ Wg,
    const float* __restrict__ bg, const float* __restrict__ Wh,
    const float* __restrict__ Wb, const float* __restrict__ Wm,
    const float* __restrict__ We, const float* __restrict__ bb,
    const float* __restrict__ bm, const float* __restrict__ be,
    const float* __restrict__ bh, const int* __restrict__ masks,
    u16* __restrict__ Xh, float* __restrict__ lmr, float* __restrict__ s0,
    u16* __restrict__ Breg, u16* __restrict__ WvT, float* __restrict__ bcat,
    float* __restrict__ u, float* __restrict__ cbuf, int* __restrict__ idx,
    int* __restrict__ perm, int* __restrict__ cnts) {
  __shared__ __align__(16) char smem_raw[32768];
  float* shmem = (float*)smem_raw;         // 4608 floats used by prep paths
  u16* As = (u16*)smem_raw;                // gemmA: 2*128*32 u16 = 16 KB
  u16* Bs = (u16*)(smem_raw + 16384);      // gemmA: 16 KB
#define TI(r, c) shmem[(r)*65 + (c)]
  const int b = blockIdx.x;
  const int t = threadIdx.x;
  if (b < 64) {
    int k0 = (b & 7) * 64;
    int n0 = (b >> 3) * 64;
#pragma unroll
    for (int i = 0; i < 16; i++) {
      int li = i * 256 + t; int r = li >> 6, c = li & 63;
      TI(r, c) = Wh[(size_t)(k0 + r) * 1536 + 1024 + n0 + c];
    }
    __syncthreads();
#pragma unroll
    for (int i = 0; i < 16; i++) {
      int li = i * 256 + t; int r = li >> 6, c = li & 63;
      Breg[(size_t)(512 + n0 + r) * 512 + k0 + c] = f2h(TI(c, r));
    }
  } else if (b < 160) {
    int idx2 = b - 64;                  // [0,96)
    int ty = idx2 >> 5;
    int rem = idx2 & 31;
    int c0 = (rem & 3) * 64;
    int n0 = (rem >> 2) * 64;
    const float* Wsrc = ty == 0 ? Wb : ty == 1 ? Wm : We;
#pragma unroll
    for (int i = 0; i < 16; i++) {
      int li = i * 256 + t; int r = li >> 6, c = li & 63;
      TI(r, c) = Wsrc[(size_t)(c0 + r) * 1024 + 512 + n0 + c];
    }
    __syncthreads();
#pragma unroll
    for (int i = 0; i < 16; i++) {
      int li = i * 256 + t; int r = li >> 6, c = li & 63;
      WvT[(size_t)(n0 + r) * 768 + ty * 256 + c0 + c] = f2h(TI(c, r));
    }
  } else if (b < 516) {
    // wave-parallel dots: one wave per output scalar.
    const int lane = t & 63;
    const int widx = (b - 160) * 4 + (t >> 6);   // [0,1424)
    const int c = lane * 8;
    if (widx < 896) {
      int n = widx;
      float acc = 0.f;
      if (n < 771) {
        const float* src;
        if (n < 768) {
          int ty = n >> 8, ce = n & 255;
          src = (ty == 0 ? Wb : ty == 1 ? Wm : We) + (size_t)ce * 1024 + c;
        } else {
          int ty = n - 768;
          src = (ty == 0 ? bb : ty == 1 ? bm : be) + c;
        }
        float4 a0 = *(const float4*)src;
        float4 a1 = *(const float4*)(src + 4);
        float4 b0 = *(const float4*)(bh + c);
        float4 b1 = *(const float4*)(bh + c + 4);
        acc = a0.x * b0.x + a0.y * b0.y + a0.z * b0.z + a0.w * b0.w +
              a1.x * b1.x + a1.y * b1.y + a1.z * b1.z + a1.w * b1.w;
      }
#pragma unroll
      for (int o = 32; o > 0; o >>= 1) acc += __shfl_xor(acc, o);
      if (lane == 0) bcat[512 + n] = acc;
    } else if (widx < 1408) {
      int k = widx - 896;
      const float* wr = Wh + (size_t)k * 1536;
      float4 a0 = *(const float4*)(wr + c);
      float4 a1 = *(const float4*)(wr + c + 4);
      float4 a2 = *(const float4*)(wr + 512 + c);
      float4 a3 = *(const float4*)(wr + 512 + c + 4);
      float4 b0 = *(const float4*)(bh + 512 + c);
      float4 b1 = *(const float4*)(bh + 512 + c + 4);
      float4 b2 = *(const float4*)(bh + c);
      float4 b3 = *(const float4*)(bh + c + 4);
      float acc = a0.x * b0.x + a0.y * b0.y + a0.z * b0.z + a0.w * b0.w +
                  a1.x * b1.x + a1.y * b1.y + a1.z * b1.z + a1.w * b1.w +
                  a2.x * b2.x + a2.y * b2.y + a2.z * b2.z + a2.w * b2.w +
                  a3.x * b3.x + a3.y * b3.y + a3.z * b3.z + a3.w * b3.w;
#pragma unroll
      for (int o = 32; o > 0; o >>= 1) acc += __shfl_xor(acc, o);
      if (lane == 0) u[k] = acc;
    } else if (widx == 1408) {
      float4 b0 = *(const float4*)(bh + c);
      float4 b1 = *(const float4*)(bh + c + 4);
      float4 b2 = *(const float4*)(bh + 512 + c);
      float4 b3 = *(const float4*)(bh + 512 + c + 4);
      float acc = b0.x * b2.x + b0.y * b2.y + b0.z * b2.z + b0.w * b2.w +
                  b1.x * b3.x + b1.y * b3.y + b1.z * b3.z + b1.w * b3.w;
#pragma unroll
      for (int o = 32; o > 0; o >>= 1) acc += __shfl_xor(acc, o);
      if (lane == 0) cbuf[0] = acc;
    } else if (widx < 1417) {
      int i = (widx - 1409) * 64 + lane;   // [0,512)
      bcat[i] = bh[1024 + i];
    }
  } else if (b < 1028) {
    // X -> fp16  +  lmr  (+ s0 zero)
    const int xb = b - 516;              // [0,512)
    if (xb < 32) s0[xb * 256 + t] = 0.f;
    for (int i = t; i < 4608; i += 256) shmem[i] = Wg[i];
    __syncthreads();
    const int lane = t & 63, wid = t >> 6;
#pragma unroll
    for (int it = 0; it < 4; it++) {
      int pos = xb * 16 + it * 4 + wid;
      const float* x = X + (size_t)pos * 512 + lane * 8;
      float4 x0 = *(const float4*)x;
      float4 x1 = *(const float4*)(x + 4);
      float xs[8] = {x0.x, x0.y, x0.z, x0.w, x1.x, x1.y, x1.z, x1.w};
      ushort4 h0, h1;
      h0.x = f2h(xs[0]); h0.y = f2h(xs[1]); h0.z = f2h(xs[2]); h0.w = f2h(xs[3]);
      h1.x = f2h(xs[4]); h1.y = f2h(xs[5]); h1.z = f2h(xs[6]); h1.w = f2h(xs[7]);
      ((ushort4*)Xh)[pos * 128 + lane * 2] = h0;
      ((ushort4*)Xh)[pos * 128 + lane * 2 + 1] = h1;
      float p[9];
#pragma unroll
      for (int c = 0; c < 9; c++) p[c] = 0.f;
      const float* wrow = shmem + (lane * 8) * 9;
#pragma unroll
      for (int j = 0; j < 8; j++)
#pragma unroll
        for (int c = 0; c < 9; c++) p[c] += xs[j] * wrow[j * 9 + c];
#pragma unroll
      for (int c = 0; c < 9; c++)
#pragma unroll
        for (int o = 32; o > 0; o >>= 1) p[c] += __shfl_xor(p[c], o);
      if (lane == 0) {
#pragma unroll
        for (int c = 0; c < 9; c++) lmr[(size_t)pos * 9 + c] = p[c] + bg[c];
      }
    }
  } else if (b < 1060) {
    // mask partition (cnts[0..1] pre-zeroed on stream)
    const int lane = t & 63;
    const int pos = (b - 1028) * 256 + t;
    bool is0 = masks[pos] == 0;
    unsigned long long bal = __ballot(is0);
    unsigned long long below = (lane == 0) ? 0ull : (~0ull >> (64 - lane));
    int rank0 = __popcll(bal & below);
    int rank1 = __popcll((~bal) & below);
    int n0w = __popcll(bal);
    int base0 = 0, base1 = 0;
    if (lane == 0) {
      base0 = atomicAdd(&cnts[0], n0w);
      base1 = atomicAdd(&cnts[1], 64 - n0w);
    }
    base0 = __shfl(base0, 0);
    base1 = __shfl(base1, 0);
    int slot = is0 ? (base0 + rank0) : (8191 - (base1 + rank1));
    perm[pos] = slot;
    idx[slot] = pos;
  } else {
    // ---- gemmA merged: Breg[M | Wcomb] = Acat @ Whq^T, staged from fp32 ----
    // A row r: r<512 -> Wh[r, 512..1024) (Whk);  r=512+n:
    //   n<768  -> W{b,m,e}[n&255, 0..512);  n in [768,771) -> b{b,m,e}[0..512)
    //   n>=771 -> zeros.
    // B row n: Wh[n, 0..512) (Whq).   Out: Breg rows 0..511 / 1024..1919.
    const int b2 = b - 1060;             // [0,44)
    const int m0 = (b2 % 11) * 128;
    const int n0 = (b2 / 11) * 128;
    const int lane = t & 63;
    const int wid = t >> 6;
    const int row = t >> 2;              // 0..63
    const int koff = (t & 3) * 8;
    const int lds0 = row * 32 + koff;
    const int lds1 = 2048 + lds0;

    auto asrc = [&](int r) -> const float* {
      if (r < 512) return Wh + (size_t)r * 1536 + 512;
      int n = r - 512;
      if (n < 768)
        return (n < 256 ? Wb : n < 512 ? Wm : We) + (size_t)(n & 255) * 1024;
      if (n < 771) return (n == 768 ? bb : n == 769 ? bm : be);
      return nullptr;
    };
    const float* pa0 = asrc(m0 + row);
    const float* pa1 = asrc(m0 + 64 + row);
    const float* pb0 = Wh + (size_t)(n0 + row) * 1536;
    const float* pb1 = Wh + (size_t)(n0 + 64 + row) * 1536;

    const int wm = (wid & 1) * 64;
    const int wn = (wid >> 1) * 64;
    const int fr = lane & 15;
    const int kq = (lane >> 4) * 8;

    f32x4 acc[4][4];
#pragma unroll
    for (int i = 0; i < 4; i++)
#pragma unroll
      for (int j = 0; j < 4; j++) acc[i][j] = (f32x4){0.f, 0.f, 0.f, 0.f};

    auto cvt8 = [&](const float* p, int col) -> f16x8 {
      f16x8 h{};
      if (p) {
        float4 v0 = *(const float4*)(p + col);
        float4 v1 = *(const float4*)(p + col + 4);
        h[0] = (f16)v0.x; h[1] = (f16)v0.y; h[2] = (f16)v0.z; h[3] = (f16)v0.w;
        h[4] = (f16)v1.x; h[5] = (f16)v1.y; h[6] = (f16)v1.z; h[7] = (f16)v1.w;
      }
      return h;
    };
    auto STAGE = [&](int kb, int buf) {
      *(f16x8*)&As[buf * 4096 + lds0] = cvt8(pa0, kb + koff);
      *(f16x8*)&As[buf * 4096 + lds1] = cvt8(pa1, kb + koff);
      *(f16x8*)&Bs[buf * 4096 + lds0] = cvt8(pb0, kb + koff);
      *(f16x8*)&Bs[buf * 4096 + lds1] = cvt8(pb1, kb + koff);
    };
    auto COMPUTE = [&](int buf) {
      f16x8 av[4], bv[4];
#pragma unroll
      for (int i = 0; i < 4; i++) {
        av[i] = *(const f16x8*)&As[buf * 4096 + (wm + i * 16 + fr) * 32 + kq];
        bv[i] = *(const f16x8*)&Bs[buf * 4096 + (wn + i * 16 + fr) * 32 + kq];
      }
#pragma unroll
      for (int mt = 0; mt < 4; mt++)
#pragma unroll
        for (int nt = 0; nt < 4; nt++)
          acc[mt][nt] = __builtin_amdgcn_mfma_f32_16x16x32_f16(
              av[mt], bv[nt], acc[mt][nt], 0, 0, 0);
    };

    STAGE(0, 0);
    __syncthreads();
    int buf = 0;
    for (int ki = 0; ki < 15; ++ki) {     // K=512 -> 16 panels of 32
      STAGE((ki + 1) * 32, buf ^ 1);
      COMPUTE(buf);
      __syncthreads();
      buf ^= 1;
    }
    COMPUTE(buf);

    const int r0 = (lane >> 4) * 4;
#pragma unroll
    for (int mt = 0; mt < 4; mt++)
#pragma unroll
      for (int nt = 0; nt < 4; nt++) {
        int col = n0 + wn + nt * 16 + fr;
#pragma unroll
        for (int r = 0; r < 4; r++) {
          int orow0 = m0 + wm + mt * 16 + r0 + r;
          int orow = orow0 < 512 ? orow0 : orow0 + 512;  // Wcomb -> 1024..1919
          Breg[(size_t)orow * 512 + col] = f2h(acc[mt][nt][r]);
        }
      }
  }
#undef TI
}

// ---------------- unified fp16 MFMA GEMM, double-buffered BK=32 -------------
// 128xBN tile, 4 waves (2x2).  MODE 0: BN=128, per-wave 4x4 of 16x16x32.
// MODE 2: BN=64 (grid 64x8 -> 2 blocks/CU), per-wave 4x2.
// K-loop: prefetch tile k+1 into buf^1, compute buf, one barrier per 32-K.
// MODE 0 (gemmB, 64x15):
//   y<4:  group0 slots; A rows = Xh[idx[slot]]; s0c[slot] += rowdot(.+u, Xh)
//   y4-7: all rows pos space; HPb[row*1408 + col] = f2h(acc + bcat[col])
//   y>=8: group1 slots; A rows = Xh[idx[slot]]; HPb[slot*1408+512+pcol]
// MODE 2 (gemmC, 64x8):  out = sc4.x*hv + sc4.{y,z,w}.bv + acc
template <int MODE>
__global__ __launch_bounds__(256) void gemm_k(
    const u16* __restrict__ A, const u16* __restrict__ Bt,
    const float* __restrict__ ubias, const float* __restrict__ bcat,
    float* __restrict__ Cf, u16* __restrict__ Cb, int Kdim,
    const u16* __restrict__ Xh, float* __restrict__ s0c,
    const int* __restrict__ idx, const int* __restrict__ cnts,
    const float4* __restrict__ sc4, const u16* __restrict__ HPb,
    const float* __restrict__ bb, const float* __restrict__ bm,
    const float* __restrict__ be) {
  constexpr int BROWS = (MODE == 2) ? 64 : 128;   // B-rows (tile N width)
  constexpr int NT = (MODE == 2) ? 2 : 4;         // per-wave 16-col tiles
  __shared__ __align__(16) u16 As[2 * 128 * 32];
  __shared__ __align__(16) u16 Bs[2 * BROWS * 32];

  const int t = threadIdx.x;
  const int lane = t & 63;
  const int wid = t >> 6;
  const int m0 = blockIdx.x * 128;
  const int n0 = blockIdx.y * BROWS;

  bool remap = false;
  if constexpr (MODE == 0) {
    const int cnt0 = cnts[0];
    if (blockIdx.y < 4) {
      if (m0 >= cnt0) return;          // group0 only
      remap = true;
    } else if (blockIdx.y >= 8) {
      if (m0 + 128 <= cnt0) return;    // group1 only
      remap = true;
    }
  }

  // staged rows: A rows r, r+64; B rows r (+64 when BROWS==128)
  int ra0 = m0 + (t >> 2), ra1 = m0 + 64 + (t >> 2);
  if (MODE == 0 && remap) { ra0 = idx[ra0]; ra1 = idx[ra1]; }
  const int rb0 = n0 + (t >> 2), rb1 = n0 + 64 + (t >> 2);
  const int koff = (t & 3) * 8;
  const int lds0 = (t >> 2) * 32 + koff;       // rows 0..63 slot (lane*16B)
  const int lds1 = 2048 + lds0;                // rows 64..127

  const int wm = (wid & 1) * 64;
  const int wn = (wid >> 1) * (NT * 16);
  const int fr = lane & 15;
  const int kq = (lane >> 4) * 8;

  f32x4 acc[4][NT];
#pragma unroll
  for (int i = 0; i < 4; i++)
#pragma unroll
    for (int j = 0; j < NT; j++) acc[i][j] = (f32x4){0.f, 0.f, 0.f, 0.f};

  auto STAGE = [&](int kb, int buf) {
    gl2lds(&A[(size_t)ra0 * Kdim + kb], &As[buf * 4096 + lds0]);
    gl2lds(&A[(size_t)ra1 * Kdim + kb], &As[buf * 4096 + lds1]);
    gl2lds(&Bt[(size_t)rb0 * Kdim + kb], &Bs[buf * (BROWS * 32) + lds0]);
    if constexpr (BROWS == 128)
      gl2lds(&Bt[(size_t)rb1 * Kdim + kb], &Bs[buf * (BROWS * 32) + lds1]);
  };
  auto COMPUTE = [&](int buf) {
    f16x8 av[4], bv[NT];
#pragma unroll
    for (int i = 0; i < 4; i++)
      av[i] = *(const f16x8*)&As[buf * 4096 + (wm + i * 16 + fr) * 32 + kq];
#pragma unroll
    for (int j = 0; j < NT; j++)
      bv[j] = *(const f16x8*)&Bs[buf * (BROWS * 32) + (wn + j * 16 + fr) * 32 + kq];
#pragma unroll
    for (int mt = 0; mt < 4; mt++)
#pragma unroll
      for (int nt = 0; nt < NT; nt++)
        acc[mt][nt] = __builtin_amdgcn_mfma_f32_16x16x32_f16(
            av[mt], bv[nt], acc[mt][nt], 0, 0, 0);
  };

  // 2-phase pipeline: stage(k+1) overlaps compute(k); one barrier per tile.
  STAGE(koff, 0);
  __syncthreads();
  const int nk = Kdim >> 5;
  int buf = 0;
  for (int ki = 0; ki < nk - 1; ++ki) {
    STAGE((ki + 1) * 32 + koff, buf ^ 1);
    COMPUTE(buf);
    __syncthreads();
    buf ^= 1;
  }
  COMPUTE(buf);

  const int r0 = (lane >> 4) * 4;
  if constexpr (MODE == 0) {
    if (blockIdx.y < 4) {
      float pl[4][4];
      int xrow[4][4];
#pragma unroll
      for (int mt = 0; mt < 4; mt++)
#pragma unroll
        for (int r = 0; r < 4; r++) {
          pl[mt][r] = 0.f;
          xrow[mt][r] = idx[m0 + wm + mt * 16 + r0 + r];
        }
#pragma unroll
      for (int mt = 0; mt < 4; mt++)
#pragma unroll
        for (int nt = 0; nt < 4; nt++) {
          int col = n0 + wn + nt * 16 + fr;
          float bv2 = ubias[col];
#pragma unroll
          for (int r = 0; r < 4; r++)
            pl[mt][r] += (acc[mt][nt][r] + bv2) *
                         h2f(Xh[(size_t)xrow[mt][r] * 512 + col]);
        }
#pragma unroll
      for (int mt = 0; mt < 4; mt++)
#pragma unroll
        for (int r = 0; r < 4; r++) {
          float p = pl[mt][r];
          p += __shfl_xor(p, 1);
          p += __shfl_xor(p, 2);
          p += __shfl_xor(p, 4);
          p += __shfl_xor(p, 8);
          if (fr == r) {
            int slot = m0 + wm + mt * 16 + r0 + r;
            atomicAdd(&s0c[slot], p);
          }
        }
      return;
    }
    if (blockIdx.y < 8) {
#pragma unroll
      for (int mt = 0; mt < 4; mt++)
#pragma unroll
        for (int nt = 0; nt < 4; nt++) {
          int col = n0 - 512 + wn + nt * 16 + fr;
          float bv2 = bcat[col];
#pragma unroll
          for (int r = 0; r < 4; r++) {
            int row = m0 + wm + mt * 16 + r0 + r;
            Cb[(size_t)row * 1408 + col] = f2h(acc[mt][nt][r] + bv2);
          }
        }
    } else {
#pragma unroll
      for (int mt = 0; mt < 4; mt++)
#pragma unroll
        for (int nt = 0; nt < 4; nt++) {
          int pcol = n0 - 1024 + wn + nt * 16 + fr;
          float bv2 = bcat[512 + pcol];
#pragma unroll
          for (int r = 0; r < 4; r++) {
            int slot = m0 + wm + mt * 16 + r0 + r;
            Cb[(size_t)slot * 1408 + 512 + pcol] = f2h(acc[mt][nt][r] + bv2);
          }
        }
    }
  } else {
#pragma unroll
    for (int mt = 0; mt < 4; mt++)
#pragma unroll
      for (int nt = 0; nt < NT; nt++) {
        int col = n0 + wn + nt * 16 + fr;
        float b0 = bb[512 + col];
        float b1 = bm[512 + col];
        float b2 = be[512 + col];
#pragma unroll
        for (int r = 0; r < 4; r++) {
          int row = m0 + wm + mt * 16 + r0 + r;
          float4 s = sc4[row];
          float hv = h2f(HPb[(size_t)row * 1408 + col]);
          Cf[(size_t)row * 512 + col] =
              s.x * hv + s.y * b0 + s.z * b1 + s.w * b2 + acc[mt][nt][r];
        }
      }
  }
}

// ---------------- fused gather / scores / softmax / aggregate ---------------
__global__ __launch_bounds__(256) void attn_kernel(
    const int* __restrict__ masks, const int* __restrict__ begins,
    const int* __restrict__ blens, const int* __restrict__ middles,
    const int* __restrict__ mlens, const int* __restrict__ ends,
    const int* __restrict__ elens, const float* __restrict__ emb,
    const u16* __restrict__ HPb, const float* __restrict__ lmr,
    const float* __restrict__ s0buf, const float* __restrict__ cbuf,
    const int* __restrict__ perm, float4* __restrict__ sc4,
    u16* __restrict__ Ebar) {
  const int t = threadIdx.x;
  const int lane = t & 63;
  const int wid = t >> 6;
  const int pos = blockIdx.x * 4 + wid;
  const int mask = masks[pos];
  const int slot = perm[pos];
  u16* erow = Ebar + (size_t)pos * 768;

  int l0 = min(blens[pos], 5), l1 = min(mlens[pos], 5), l2 = min(elens[pos], 5);
  int nv = l0 + l1 + l2;

  if (mask == 0) {
    float s0 = s0buf[slot] + cbuf[0];
    int ninv = 15 - nv;
    float w0;
    if (ninv == 0) {
      w0 = 1.f;
    } else {
      float Mx = fmaxf(s0, 0.f);
      float e0 = __expf(s0 - Mx);
      w0 = e0 / (e0 + (float)ninv * __expf(-Mx));
    }
    if (lane == 0) sc4[pos] = make_float4(w0, 0.f, 0.f, 0.f);
    ushort4 zz; zz.x = zz.y = zz.z = zz.w = 0;
    *(ushort4*)(erow + 0 * 256 + lane * 4) = zz;
    *(ushort4*)(erow + 1 * 256 + lane * 4) = zz;
    *(ushort4*)(erow + 2 * 256 + lane * 4) = zz;
  } else {
    const int s = pos & (SS - 1);
    float g[3];
    if (s == 0 || s == SS - 1) {
      g[0] = 1.f; g[1] = 0.f; g[2] = 1.f;
    } else {
      const float* p0 = lmr + (size_t)(pos - 1) * 9;
      const float* p1 = lmr + (size_t)pos * 9;
      const float* p2 = lmr + (size_t)(pos + 1) * 9;
      g[0] = sigm(p0[0] + p1[3] + p2[6]);
      g[1] = sigm(p0[1] + p1[4] + p2[7]);
      g[2] = sigm(p0[2] + p1[5] + p2[8]);
    }
    const bool deg = (nv == 15);
    int l[3] = {l0, l1, l2};
    if (deg) { l[0] = 0; l[1] = 0; l[2] = 0; }

    float4 Pt[3];
    float qb[3];
    if (!deg) {
      const u16* prow = HPb + (size_t)slot * 1408 + 512;
#pragma unroll
      for (int ty = 0; ty < 3; ty++) {
        ushort4 pu = *(const ushort4*)(prow + ty * 256 + lane * 4);
        Pt[ty].x = h2f(pu.x); Pt[ty].y = h2f(pu.y);
        Pt[ty].z = h2f(pu.z); Pt[ty].w = h2f(pu.w);
        qb[ty] = h2f(prow[768 + ty]);
      }
    }
    const int* idxp[3];
    idxp[0] = begins + (size_t)pos * 5;
    idxp[1] = middles + (size_t)pos * 5;
    idxp[2] = ends + (size_t)pos * 5;

    float4 ev[3][5];
    float scv[3][5];
    float Mx = deg ? 0.f : -3.0e38f;
#pragma unroll
    for (int ty = 0; ty < 3; ty++) {
#pragma unroll
      for (int w = 0; w < 5; w++) {
        bool act = (w >= l[ty]);      // wave-uniform
        if (act) {
          ev[ty][w] = *(const float4*)(emb + (size_t)idxp[ty][w] * 256 + lane * 4);
          float sv = 0.f;
          if (!deg) {
            float4 e = ev[ty][w];
            float d = Pt[ty].x * e.x + Pt[ty].y * e.y + Pt[ty].z * e.z + Pt[ty].w * e.w;
#pragma unroll
            for (int o = 32; o > 0; o >>= 1) d += __shfl_xor(d, o);
            sv = g[ty] * (d + qb[ty]);
          }
          scv[ty][w] = sv;
          Mx = fmaxf(Mx, sv);
        }
      }
    }
    float wts0 = deg ? 1.f : 0.f;     // hidden survives only in deg case
    float zs = wts0;
    float wts[3][5];
#pragma unroll
    for (int ty = 0; ty < 3; ty++)
#pragma unroll
      for (int w = 0; w < 5; w++) {
        bool act = (w >= l[ty]);
        float wv = act ? __expf(scv[ty][w] - Mx) : 0.f;
        wts[ty][w] = wv;
        zs += wv;
      }
    float inv = 1.f / zs;
    float alpha[3];
#pragma unroll
    for (int ty = 0; ty < 3; ty++) {
      float ax = 0.f, ay = 0.f, az = 0.f, aw = 0.f, asum = 0.f;
#pragma unroll
      for (int w = 0; w < 5; w++) {
        if (w >= l[ty]) {
          float wk = wts[ty][w];
          asum += wk;
          ax += wk * ev[ty][w].x;
          ay += wk * ev[ty][w].y;
          az += wk * ev[ty][w].z;
          aw += wk * ev[ty][w].w;
        }
      }
      float sg = g[ty] * inv;
      alpha[ty] = sg * asum;
      ushort4 h;
      h.x = f2h(ax * sg); h.y = f2h(ay * sg); h.z = f2h(az * sg); h.w = f2h(aw * sg);
      *(ushort4*)(erow + ty * 256 + lane * 4) = h;
    }
    if (lane == 0) sc4[pos] = make_float4(wts0 * inv, alpha[0], alpha[1], alpha[2]);
  }
}

// ---------------------------------------------------------------------------
extern "C" void kernel_launch(void* const* d_in, const int* in_sizes, int n_in,
                              void* d_out, int out_size, void* d_ws, size_t ws_size,
                              hipStream_t stream) {
  const float* hiddens = (const float*)d_in[0];
  const int* masks = (const int*)d_in[1];
  const int* begins = (const int*)d_in[2];
  const int* blens = (const int*)d_in[3];
  const int* middles = (const int*)d_in[4];
  const int* mlens = (const int*)d_in[5];
  const int* ends = (const int*)d_in[6];
  const int* elens = (const int*)d_in[7];
  const float* emb = (const float*)d_in[8];
  const float* Wh = (const float*)d_in[9];
  const float* bh = (const float*)d_in[10];
  const float* Wb = (const float*)d_in[11];
  const float* bb = (const float*)d_in[12];
  const float* Wm = (const float*)d_in[13];
  const float* bm = (const float*)d_in[14];
  const float* We = (const float*)d_in[15];
  const float* be = (const float*)d_in[16];
  const float* Wg = (const float*)d_in[17];
  const float* bg = (const float*)d_in[18];
  float* out = (float*)d_out;

  char* ws = (char*)d_ws;
  size_t off = 0;
  auto alloc = [&](size_t bytes) -> char* {
    char* p = ws + off;
    off += (bytes + 255) & ~(size_t)255;
    return p;
  };
  u16* Xh = (u16*)alloc((size_t)8192 * 512 * 2);
  u16* Breg = (u16*)alloc((size_t)1920 * 512 * 2);   // [M | WhvT | Wcomb]
  u16* WvT = (u16*)alloc((size_t)512 * 768 * 2);
  u16* HPb = (u16*)alloc((size_t)8192 * 1408 * 2);   // [hv fp16 | P fp16]
  float* lmr = (float*)alloc((size_t)8192 * 9 * 4);
  float* s0c = (float*)alloc((size_t)8192 * 4);
  float* bcat = (float*)alloc((size_t)1408 * 4);
  float* u = (float*)alloc((size_t)512 * 4);
  float* cbuf = (float*)alloc((size_t)4);
  float* sc4 = (float*)alloc((size_t)8192 * 4 * 4);
  u16* Ebar = (u16*)alloc((size_t)8192 * 768 * 2);
  int* idx = (int*)alloc((size_t)8192 * 4);
  int* perm = (int*)alloc((size_t)8192 * 4);
  int* cnts = (int*)alloc((size_t)256);
  if (off > ws_size) return;  // fail loudly (output stays poisoned)

  // 0) zero partition counters
  hipMemsetAsync(cnts, 0, 8, stream);
  // 1) all preps + gemmA in one launch
  prep_all<<<1104, 256, 0, stream>>>(hiddens, Wg, bg, Wh, Wb, Wm, We, bb, bm, be,
                                     bh, masks, Xh, lmr, s0c, Breg, WvT, bcat,
                                     u, cbuf, idx, perm, cnts);
  // 2) gemmB: y<4 -> s0 (group0); y4-7 -> hv (all); y>=8 -> P (group1)
  gemm_k<0><<<dim3(64, 15), 256, 0, stream>>>(
      Xh, Breg, u, bcat, nullptr, HPb, 512, Xh, s0c, idx, cnts,
      nullptr, nullptr, nullptr, nullptr, nullptr);
  // 3) fused attention -> sc4 + Ebar
  attn_kernel<<<2048, 256, 0, stream>>>(masks, begins, blens, middles, mlens,
                                        ends, elens, emb, HPb, lmr, s0c, cbuf,
                                        perm, (float4*)sc4, Ebar);
  // 4) gemmC: out = sc4 epilogue + Ebar @ WvT^T  (128x64 tiles, 2 blocks/CU)
  gemm_k<2><<<dim3(64, 8), 256, 0, stream>>>(
      Ebar, WvT, nullptr, nullptr, out, nullptr, 768, nullptr, nullptr,
      nullptr, nullptr, (const float4*)sc4, HPb, bb, bm, be);
}

// Round 4
// 275.143 us; speedup vs baseline: 1.1034x; 1.1034x over previous
//
#include <hip/hip_runtime.h>
#include <cstdint>
#include <cstddef>

// ---------------------------------------------------------------------------
// GatedLatticeLayer on MI355X.  B=16 S=512 W=5 H=512 E=256 V=100000.
// MROWS = B*S = 8192.
//
// Round 10 = Round 6 (best, 278.9us) + ONE change: gemmC retiled 128x64,
// grid 64x8 -> 2 blocks/CU (was 1 block/CU, the worst-occupancy kernel in
// the chain).  Numerics identical.  R7 (dbuf K-loop) and R8 (gemmA merge)
// regressed and are reverted; R9 (cooperative mega) failed and is reverted.
//
// Round 6 (5 launches + 8B memset), all-fp16 MFMA:
//   prep_all: X->fp16, lmr, weight transposes/copies, bias dots, mask PARTITION
//             (group0 = mask==0 slots [0,cnt0) ascending; group1 descending
//              from 8191; idx: slot->pos, perm: pos->slot; bijection => every
//              entry written, no poison reads)
//   gemmA:    Breg[M | (WhvT) | Wcomb] = Acat @ Whq^T     (fp16)
//   gemmB:    y<4:  s0c[slot] += rowdot(Xh[idx]@M^T + u, Xh[idx])  (group0 only)
//             y4-7: HPb hv cols (all rows, pos space)
//             y8+:  HPb P cols  (group1 slots only, row-remapped via idx)
//             blocks outside their group's slot range early-exit.
//   attn:     slot=perm[pos]; only INVALID candidates (w>=len) survive the
//             reference mask; deg (all 15 valid, mask!=0) -> uniform 1/16.
//   gemmC:    out = w0*hv + sum_t a_t*bv_t + Ebar @ WvT^T
// GEMMs use BK=64 as two sequential BK=32 panels (m97-identical LDS banks,
// half the barriers).
// ---------------------------------------------------------------------------

typedef unsigned short u16;
typedef _Float16 f16;
typedef __attribute__((ext_vector_type(8))) f16 f16x8;
typedef __attribute__((ext_vector_type(4))) float f32x4;

#define MROWS 8192
#define SS 512

static __device__ __forceinline__ u16 f2h(float x) {
  f16 h = (f16)x;
  return __builtin_bit_cast(u16, h);
}
static __device__ __forceinline__ float h2f(u16 h) {
  return (float)__builtin_bit_cast(f16, h);
}
static __device__ __forceinline__ float sigm(float x) { return 1.f / (1.f + __expf(-x)); }

static __device__ __forceinline__ void gl2lds(const u16* g, u16* l) {
  __builtin_amdgcn_global_load_lds(
      (const __attribute__((address_space(1))) unsigned int*)g,
      (__attribute__((address_space(3))) unsigned int*)l, 16, 0, 0);
}

// ---------------- merged prep: weights + dots + X/lmr + partition -----------
// [0,64):      WhvT -> Breg rows 512..1023 (fp16)
// [64,128):    Whq (fp16) + Whk -> Acat rows 0..511
// [128,576):   WkT -> Acat rows 512..1407
// [576,672):   WvT (512x768 fp16)
// [672,1028):  wave dots: bcat[512+n]=bcomb, u, cb, bcat[0:512) copy
// [1028,1540): X -> fp16 + lmr (+ s0 zero)
// [1540,1572): mask partition -> idx/perm (cnts pre-zeroed via memsetAsync)
__global__ __launch_bounds__(256) void prep_all(
    const float* __restrict__ X, const float* __restrict__ Wg,
    const float* __restrict__ bg, const float* __restrict__ Wh,
    const float* __restrict__ Wb, const float* __restrict__ Wm,
    const float* __restrict__ We, const float* __restrict__ bb,
    const float* __restrict__ bm, const float* __restrict__ be,
    const float* __restrict__ bh, const int* __restrict__ masks,
    u16* __restrict__ Xh, float* __restrict__ lmr, float* __restrict__ s0,
    u16* __restrict__ Breg, u16* __restrict__ Acat, u16* __restrict__ Whq,
    u16* __restrict__ WvT, float* __restrict__ bcat, float* __restrict__ u,
    float* __restrict__ cbuf, int* __restrict__ idx, int* __restrict__ perm,
    int* __restrict__ cnts) {
  __shared__ float shmem[4608];            // tile (64x65=4160) or wg (4608)
#define TI(r, c) shmem[(r)*65 + (c)]
  const int b = blockIdx.x;
  const int t = threadIdx.x;
  if (b < 64) {
    int k0 = (b & 7) * 64;
    int n0 = (b >> 3) * 64;
#pragma unroll
    for (int i = 0; i < 16; i++) {
      int li = i * 256 + t; int r = li >> 6, c = li & 63;
      TI(r, c) = Wh[(size_t)(k0 + r) * 1536 + 1024 + n0 + c];
    }
    __syncthreads();
#pragma unroll
    for (int i = 0; i < 16; i++) {
      int li = i * 256 + t; int r = li >> 6, c = li & 63;
      Breg[(size_t)(512 + n0 + r) * 512 + k0 + c] = f2h(TI(c, r));
    }
  } else if (b < 128) {
#pragma unroll
    for (int i = 0; i < 4; i++) {
      int q4 = (b - 64) * 1024 + t * 4 + i;   // [0, 65536) float4 index
      int k = q4 >> 7;
      int c4 = (q4 & 127) * 4;
      float4 vq = *(const float4*)(Wh + (size_t)k * 1536 + c4);
      float4 vk = *(const float4*)(Wh + (size_t)k * 1536 + 512 + c4);
      ushort4 qh, kh;
      qh.x = f2h(vq.x); qh.y = f2h(vq.y); qh.z = f2h(vq.z); qh.w = f2h(vq.w);
      kh.x = f2h(vk.x); kh.y = f2h(vk.y); kh.z = f2h(vk.z); kh.w = f2h(vk.w);
      size_t o = (size_t)k * 512 + c4;
      *(ushort4*)(Whq + o) = qh;
      *(ushort4*)(Acat + o) = kh;
    }
  } else if (b < 576) {
    int tid = (b - 128) * 256 + t;      // [0, 896*128)
    int n = tid >> 7;
    int kq = (tid & 127) * 4;
    float4 v;
    if (n < 768) {
      int ty = n >> 8, c = n & 255;
      const float* src = (ty == 0 ? Wb : ty == 1 ? Wm : We) + (size_t)c * 1024 + kq;
      v = *(const float4*)src;
    } else if (n < 771) {
      int ty = n - 768;
      const float* src = (ty == 0 ? bb : ty == 1 ? bm : be) + kq;
      v = *(const float4*)src;
    } else {
      v = make_float4(0.f, 0.f, 0.f, 0.f);
    }
    ushort4 h; h.x = f2h(v.x); h.y = f2h(v.y); h.z = f2h(v.z); h.w = f2h(v.w);
    ((ushort4*)(Acat + (size_t)512 * 512))[tid] = h;
  } else if (b < 672) {
    int idx2 = b - 576;                 // [0,96)
    int ty = idx2 >> 5;
    int rem = idx2 & 31;
    int c0 = (rem & 3) * 64;
    int n0 = (rem >> 2) * 64;
    const float* Wsrc = ty == 0 ? Wb : ty == 1 ? Wm : We;
#pragma unroll
    for (int i = 0; i < 16; i++) {
      int li = i * 256 + t; int r = li >> 6, c = li & 63;
      TI(r, c) = Wsrc[(size_t)(c0 + r) * 1024 + 512 + n0 + c];
    }
    __syncthreads();
#pragma unroll
    for (int i = 0; i < 16; i++) {
      int li = i * 256 + t; int r = li >> 6, c = li & 63;
      WvT[(size_t)(n0 + r) * 768 + ty * 256 + c0 + c] = f2h(TI(c, r));
    }
  } else if (b < 1028) {
    // wave-parallel dots: one wave per output scalar.
    const int lane = t & 63;
    const int widx = (b - 672) * 4 + (t >> 6);   // [0,1424)
    const int c = lane * 8;
    if (widx < 896) {
      int n = widx;
      float acc = 0.f;
      if (n < 771) {
        const float* src;
        if (n < 768) {
          int ty = n >> 8, ce = n & 255;
          src = (ty == 0 ? Wb : ty == 1 ? Wm : We) + (size_t)ce * 1024 + c;
        } else {
          int ty = n - 768;
          src = (ty == 0 ? bb : ty == 1 ? bm : be) + c;
        }
        float4 a0 = *(const float4*)src;
        float4 a1 = *(const float4*)(src + 4);
        float4 b0 = *(const float4*)(bh + c);
        float4 b1 = *(const float4*)(bh + c + 4);
        acc = a0.x * b0.x + a0.y * b0.y + a0.z * b0.z + a0.w * b0.w +
              a1.x * b1.x + a1.y * b1.y + a1.z * b1.z + a1.w * b1.w;
      }
#pragma unroll
      for (int o = 32; o > 0; o >>= 1) acc += __shfl_xor(acc, o);
      if (lane == 0) bcat[512 + n] = acc;
    } else if (widx < 1408) {
      int k = widx - 896;
      const float* wr = Wh + (size_t)k * 1536;
      float4 a0 = *(const float4*)(wr + c);
      float4 a1 = *(const float4*)(wr + c + 4);
      float4 a2 = *(const float4*)(wr + 512 + c);
      float4 a3 = *(const float4*)(wr + 512 + c + 4);
      float4 b0 = *(const float4*)(bh + 512 + c);
      float4 b1 = *(const float4*)(bh + 512 + c + 4);
      float4 b2 = *(const float4*)(bh + c);
      float4 b3 = *(const float4*)(bh + c + 4);
      float acc = a0.x * b0.x + a0.y * b0.y + a0.z * b0.z + a0.w * b0.w +
                  a1.x * b1.x + a1.y * b1.y + a1.z * b1.z + a1.w * b1.w +
                  a2.x * b2.x + a2.y * b2.y + a2.z * b2.z + a2.w * b2.w +
                  a3.x * b3.x + a3.y * b3.y + a3.z * b3.z + a3.w * b3.w;
#pragma unroll
      for (int o = 32; o > 0; o >>= 1) acc += __shfl_xor(acc, o);
      if (lane == 0) u[k] = acc;
    } else if (widx == 1408) {
      float4 b0 = *(const float4*)(bh + c);
      float4 b1 = *(const float4*)(bh + c + 4);
      float4 b2 = *(const float4*)(bh + 512 + c);
      float4 b3 = *(const float4*)(bh + 512 + c + 4);
      float acc = b0.x * b2.x + b0.y * b2.y + b0.z * b2.z + b0.w * b2.w +
                  b1.x * b3.x + b1.y * b3.y + b1.z * b3.z + b1.w * b3.w;
#pragma unroll
      for (int o = 32; o > 0; o >>= 1) acc += __shfl_xor(acc, o);
      if (lane == 0) cbuf[0] = acc;
    } else if (widx < 1417) {
      int i = (widx - 1409) * 64 + lane;   // [0,512)
      bcat[i] = bh[1024 + i];
    }
  } else if (b < 1540) {
    // X -> fp16  +  lmr  (+ s0 zero)
    const int xb = b - 1028;             // [0,512)
    if (xb < 32) s0[xb * 256 + t] = 0.f;
    for (int i = t; i < 4608; i += 256) shmem[i] = Wg[i];
    __syncthreads();
    const int lane = t & 63, wid = t >> 6;
#pragma unroll
    for (int it = 0; it < 4; it++) {
      int pos = xb * 16 + it * 4 + wid;
      const float* x = X + (size_t)pos * 512 + lane * 8;
      float4 x0 = *(const float4*)x;
      float4 x1 = *(const float4*)(x + 4);
      float xs[8] = {x0.x, x0.y, x0.z, x0.w, x1.x, x1.y, x1.z, x1.w};
      ushort4 h0, h1;
      h0.x = f2h(xs[0]); h0.y = f2h(xs[1]); h0.z = f2h(xs[2]); h0.w = f2h(xs[3]);
      h1.x = f2h(xs[4]); h1.y = f2h(xs[5]); h1.z = f2h(xs[6]); h1.w = f2h(xs[7]);
      ((ushort4*)Xh)[pos * 128 + lane * 2] = h0;
      ((ushort4*)Xh)[pos * 128 + lane * 2 + 1] = h1;
      float p[9];
#pragma unroll
      for (int c = 0; c < 9; c++) p[c] = 0.f;
      const float* wrow = shmem + (lane * 8) * 9;
#pragma unroll
      for (int j = 0; j < 8; j++)
#pragma unroll
        for (int c = 0; c < 9; c++) p[c] += xs[j] * wrow[j * 9 + c];
#pragma unroll
      for (int c = 0; c < 9; c++)
#pragma unroll
        for (int o = 32; o > 0; o >>= 1) p[c] += __shfl_xor(p[c], o);
      if (lane == 0) {
#pragma unroll
        for (int c = 0; c < 9; c++) lmr[(size_t)pos * 9 + c] = p[c] + bg[c];
      }
    }
  } else {
    // mask partition (cnts[0..1] pre-zeroed on stream)
    const int lane = t & 63;
    const int pos = (b - 1540) * 256 + t;
    bool is0 = masks[pos] == 0;
    unsigned long long bal = __ballot(is0);
    unsigned long long below = (lane == 0) ? 0ull : (~0ull >> (64 - lane));
    int rank0 = __popcll(bal & below);
    int rank1 = __popcll((~bal) & below);
    int n0w = __popcll(bal);
    int base0 = 0, base1 = 0;
    if (lane == 0) {
      base0 = atomicAdd(&cnts[0], n0w);
      base1 = atomicAdd(&cnts[1], 64 - n0w);
    }
    base0 = __shfl(base0, 0);
    base1 = __shfl(base1, 0);
    int slot = is0 ? (base0 + rank0) : (8191 - (base1 + rank1));
    perm[pos] = slot;
    idx[slot] = pos;
  }
#undef TI
}

// ---------------- unified fp16 MFMA GEMM (BK=64 as 2x BK=32 panels) ---------
// 128xBN tile, 4 waves (2x2).  MODE 0/1: BN=128 (4x4 MFMA/wave);
// MODE 2: BN=64 (4x2 MFMA/wave, grid 64x8 -> 2 blocks/CU).
// MODE 0 (gemmB, 64x15):
//   y<4:  group0 slots; A rows = Xh[idx[slot]]; s0c[slot] += rowdot(.+u, Xh)
//   y4-7: all rows pos space; HPb[row*1408 + col] = f2h(acc + bcat[col])
//   y>=8: group1 slots; A rows = Xh[idx[slot]]; HPb[slot*1408+512+pcol]
// MODE 1 (gemmA, 11x4):  fp16 out ld512; rows >=512 remapped +512 (Wcomb)
// MODE 2 (gemmC, 64x8):  out = sc4.x*hv + sc4.{y,z,w}.bv + acc
template <int MODE>
__global__ __launch_bounds__(256) void gemm_k(
    const u16* __restrict__ A, const u16* __restrict__ Bt,
    const float* __restrict__ ubias, const float* __restrict__ bcat,
    float* __restrict__ Cf, u16* __restrict__ Cb, int Kdim,
    const u16* __restrict__ Xh, float* __restrict__ s0c,
    const int* __restrict__ idx, const int* __restrict__ cnts,
    const float4* __restrict__ sc4, const u16* __restrict__ HPb,
    const float* __restrict__ bb, const float* __restrict__ bm,
    const float* __restrict__ be) {
  constexpr int BROWS = (MODE == 2) ? 64 : 128;   // tile N width
  constexpr int NT = (MODE == 2) ? 2 : 4;         // per-wave 16-col tiles
  constexpr int BP = BROWS * 32;                  // B panel size (u16)
  __shared__ __align__(16) u16 As[2 * 128 * 32];
  __shared__ __align__(16) u16 Bs[2 * BP];

  const int t = threadIdx.x;
  const int lane = t & 63;
  const int wid = t >> 6;
  const int m0 = blockIdx.x * 128;
  const int n0 = blockIdx.y * BROWS;

  bool remap = false;
  if constexpr (MODE == 0) {
    const int cnt0 = cnts[0];
    if (blockIdx.y < 4) {
      if (m0 >= cnt0) return;          // group0 only
      remap = true;
    } else if (blockIdx.y >= 8) {
      if (m0 + 128 <= cnt0) return;    // group1 only
      remap = true;
    }
  }

  // two A rows + B rows staged per thread (rows r, r+64), koff chunk
  int ra0 = m0 + (t >> 2), ra1 = m0 + 64 + (t >> 2);
  if (MODE == 0 && remap) { ra0 = idx[ra0]; ra1 = idx[ra1]; }
  const int rb0 = n0 + (t >> 2), rb1 = n0 + 64 + (t >> 2);
  const int koff = (t & 3) * 8;
  const int lds0 = (t >> 2) * 32 + koff;       // rows 0..63 panel slot
  const int lds1 = 2048 + lds0;                // rows 64..127

  const int wm = (wid & 1) * 64;
  const int wn = (wid >> 1) * (NT * 16);
  const int fr = lane & 15;
  const int kq = (lane >> 4) * 8;

  f32x4 acc[4][NT];
#pragma unroll
  for (int i = 0; i < 4; i++)
#pragma unroll
    for (int j = 0; j < NT; j++) acc[i][j] = (f32x4){0.f, 0.f, 0.f, 0.f};

  for (int k0 = 0; k0 < Kdim; k0 += 64) {
    __syncthreads();
#pragma unroll
    for (int pn = 0; pn < 2; pn++) {
      const int kb = k0 + pn * 32 + koff;
      gl2lds(&A[(size_t)ra0 * Kdim + kb], &As[pn * 4096 + lds0]);
      gl2lds(&A[(size_t)ra1 * Kdim + kb], &As[pn * 4096 + lds1]);
      gl2lds(&Bt[(size_t)rb0 * Kdim + kb], &Bs[pn * BP + lds0]);
      if constexpr (BROWS == 128)
        gl2lds(&Bt[(size_t)rb1 * Kdim + kb], &Bs[pn * BP + lds1]);
    }
    __syncthreads();
#pragma unroll
    for (int pn = 0; pn < 2; pn++) {
      f16x8 av[4], bv[NT];
#pragma unroll
      for (int i = 0; i < 4; i++)
        av[i] = *(const f16x8*)&As[pn * 4096 + (wm + i * 16 + fr) * 32 + kq];
#pragma unroll
      for (int j = 0; j < NT; j++)
        bv[j] = *(const f16x8*)&Bs[pn * BP + (wn + j * 16 + fr) * 32 + kq];
#pragma unroll
      for (int mt = 0; mt < 4; mt++)
#pragma unroll
        for (int nt = 0; nt < NT; nt++)
          acc[mt][nt] = __builtin_amdgcn_mfma_f32_16x16x32_f16(
              av[mt], bv[nt], acc[mt][nt], 0, 0, 0);
    }
  }

  const int r0 = (lane >> 4) * 4;
  if constexpr (MODE == 0) {
    if (blockIdx.y < 4) {
      float pl[4][4];
      int xrow[4][4];
#pragma unroll
      for (int mt = 0; mt < 4; mt++)
#pragma unroll
        for (int r = 0; r < 4; r++) {
          pl[mt][r] = 0.f;
          xrow[mt][r] = idx[m0 + wm + mt * 16 + r0 + r];
        }
#pragma unroll
      for (int mt = 0; mt < 4; mt++)
#pragma unroll
        for (int nt = 0; nt < 4; nt++) {
          int col = n0 + wn + nt * 16 + fr;
          float bv2 = ubias[col];
#pragma unroll
          for (int r = 0; r < 4; r++)
            pl[mt][r] += (acc[mt][nt][r] + bv2) *
                         h2f(Xh[(size_t)xrow[mt][r] * 512 + col]);
        }
#pragma unroll
      for (int mt = 0; mt < 4; mt++)
#pragma unroll
        for (int r = 0; r < 4; r++) {
          float p = pl[mt][r];
          p += __shfl_xor(p, 1);
          p += __shfl_xor(p, 2);
          p += __shfl_xor(p, 4);
          p += __shfl_xor(p, 8);
          if (fr == r) {
            int slot = m0 + wm + mt * 16 + r0 + r;
            atomicAdd(&s0c[slot], p);
          }
        }
      return;
    }
    if (blockIdx.y < 8) {
#pragma unroll
      for (int mt = 0; mt < 4; mt++)
#pragma unroll
        for (int nt = 0; nt < 4; nt++) {
          int col = n0 - 512 + wn + nt * 16 + fr;
          float bv2 = bcat[col];
#pragma unroll
          for (int r = 0; r < 4; r++) {
            int row = m0 + wm + mt * 16 + r0 + r;
            Cb[(size_t)row * 1408 + col] = f2h(acc[mt][nt][r] + bv2);
          }
        }
    } else {
#pragma unroll
      for (int mt = 0; mt < 4; mt++)
#pragma unroll
        for (int nt = 0; nt < 4; nt++) {
          int pcol = n0 - 1024 + wn + nt * 16 + fr;
          float bv2 = bcat[512 + pcol];
#pragma unroll
          for (int r = 0; r < 4; r++) {
            int slot = m0 + wm + mt * 16 + r0 + r;
            Cb[(size_t)slot * 1408 + 512 + pcol] = f2h(acc[mt][nt][r] + bv2);
          }
        }
    }
  } else if constexpr (MODE == 1) {
#pragma unroll
    for (int mt = 0; mt < 4; mt++)
#pragma unroll
      for (int nt = 0; nt < 4; nt++) {
        int col = n0 + wn + nt * 16 + fr;
#pragma unroll
        for (int r = 0; r < 4; r++) {
          int row = m0 + wm + mt * 16 + r0 + r;
          int orow = row < 512 ? row : row + 512;   // Wcomb rows -> 1024..1919
          Cb[(size_t)orow * 512 + col] = f2h(acc[mt][nt][r]);
        }
      }
  } else {
#pragma unroll
    for (int mt = 0; mt < 4; mt++)
#pragma unroll
      for (int nt = 0; nt < NT; nt++) {
        int col = n0 + wn + nt * 16 + fr;
        float b0 = bb[512 + col];
        float b1 = bm[512 + col];
        float b2 = be[512 + col];
#pragma unroll
        for (int r = 0; r < 4; r++) {
          int row = m0 + wm + mt * 16 + r0 + r;
          float4 s = sc4[row];
          float hv = h2f(HPb[(size_t)row * 1408 + col]);
          Cf[(size_t)row * 512 + col] =
              s.x * hv + s.y * b0 + s.z * b1 + s.w * b2 + acc[mt][nt][r];
        }
      }
  }
}

// ---------------- fused gather / scores / softmax / aggregate ---------------
__global__ __launch_bounds__(256) void attn_kernel(
    const int* __restrict__ masks, const int* __restrict__ begins,
    const int* __restrict__ blens, const int* __restrict__ middles,
    const int* __restrict__ mlens, const int* __restrict__ ends,
    const int* __restrict__ elens, const float* __restrict__ emb,
    const u16* __restrict__ HPb, const float* __restrict__ lmr,
    const float* __restrict__ s0buf, const float* __restrict__ cbuf,
    const int* __restrict__ perm, float4* __restrict__ sc4,
    u16* __restrict__ Ebar) {
  const int t = threadIdx.x;
  const int lane = t & 63;
  const int wid = t >> 6;
  const int pos = blockIdx.x * 4 + wid;
  const int mask = masks[pos];
  const int slot = perm[pos];
  u16* erow = Ebar + (size_t)pos * 768;

  int l0 = min(blens[pos], 5), l1 = min(mlens[pos], 5), l2 = min(elens[pos], 5);
  int nv = l0 + l1 + l2;

  if (mask == 0) {
    float s0 = s0buf[slot] + cbuf[0];
    int ninv = 15 - nv;
    float w0;
    if (ninv == 0) {
      w0 = 1.f;
    } else {
      float Mx = fmaxf(s0, 0.f);
      float e0 = __expf(s0 - Mx);
      w0 = e0 / (e0 + (float)ninv * __expf(-Mx));
    }
    if (lane == 0) sc4[pos] = make_float4(w0, 0.f, 0.f, 0.f);
    ushort4 zz; zz.x = zz.y = zz.z = zz.w = 0;
    *(ushort4*)(erow + 0 * 256 + lane * 4) = zz;
    *(ushort4*)(erow + 1 * 256 + lane * 4) = zz;
    *(ushort4*)(erow + 2 * 256 + lane * 4) = zz;
  } else {
    const int s = pos & (SS - 1);
    float g[3];
    if (s == 0 || s == SS - 1) {
      g[0] = 1.f; g[1] = 0.f; g[2] = 1.f;
    } else {
      const float* p0 = lmr + (size_t)(pos - 1) * 9;
      const float* p1 = lmr + (size_t)pos * 9;
      const float* p2 = lmr + (size_t)(pos + 1) * 9;
      g[0] = sigm(p0[0] + p1[3] + p2[6]);
      g[1] = sigm(p0[1] + p1[4] + p2[7]);
      g[2] = sigm(p0[2] + p1[5] + p2[8]);
    }
    const bool deg = (nv == 15);
    int l[3] = {l0, l1, l2};
    if (deg) { l[0] = 0; l[1] = 0; l[2] = 0; }

    float4 Pt[3];
    float qb[3];
    if (!deg) {
      const u16* prow = HPb + (size_t)slot * 1408 + 512;
#pragma unroll
      for (int ty = 0; ty < 3; ty++) {
        ushort4 pu = *(const ushort4*)(prow + ty * 256 + lane * 4);
        Pt[ty].x = h2f(pu.x); Pt[ty].y = h2f(pu.y);
        Pt[ty].z = h2f(pu.z); Pt[ty].w = h2f(pu.w);
        qb[ty] = h2f(prow[768 + ty]);
      }
    }
    const int* idxp[3];
    idxp[0] = begins + (size_t)pos * 5;
    idxp[1] = middles + (size_t)pos * 5;
    idxp[2] = ends + (size_t)pos * 5;

    float4 ev[3][5];
    float scv[3][5];
    float Mx = deg ? 0.f : -3.0e38f;
#pragma unroll
    for (int ty = 0; ty < 3; ty++) {
#pragma unroll
      for (int w = 0; w < 5; w++) {
        bool act = (w >= l[ty]);      // wave-uniform
        if (act) {
          ev[ty][w] = *(const float4*)(emb + (size_t)idxp[ty][w] * 256 + lane * 4);
          float sv = 0.f;
          if (!deg) {
            float4 e = ev[ty][w];
            float d = Pt[ty].x * e.x + Pt[ty].y * e.y + Pt[ty].z * e.z + Pt[ty].w * e.w;
#pragma unroll
            for (int o = 32; o > 0; o >>= 1) d += __shfl_xor(d, o);
            sv = g[ty] * (d + qb[ty]);
          }
          scv[ty][w] = sv;
          Mx = fmaxf(Mx, sv);
        }
      }
    }
    float wts0 = deg ? 1.f : 0.f;     // hidden survives only in deg case
    float zs = wts0;
    float wts[3][5];
#pragma unroll
    for (int ty = 0; ty < 3; ty++)
#pragma unroll
      for (int w = 0; w < 5; w++) {
        bool act = (w >= l[ty]);
        float wv = act ? __expf(scv[ty][w] - Mx) : 0.f;
        wts[ty][w] = wv;
        zs += wv;
      }
    float inv = 1.f / zs;
    float alpha[3];
#pragma unroll
    for (int ty = 0; ty < 3; ty++) {
      float ax = 0.f, ay = 0.f, az = 0.f, aw = 0.f, asum = 0.f;
#pragma unroll
      for (int w = 0; w < 5; w++) {
        if (w >= l[ty]) {
          float wk = wts[ty][w];
          asum += wk;
          ax += wk * ev[ty][w].x;
          ay += wk * ev[ty][w].y;
          az += wk * ev[ty][w].z;
          aw += wk * ev[ty][w].w;
        }
      }
      float sg = g[ty] * inv;
      alpha[ty] = sg * asum;
      ushort4 h;
      h.x = f2h(ax * sg); h.y = f2h(ay * sg); h.z = f2h(az * sg); h.w = f2h(aw * sg);
      *(ushort4*)(erow + ty * 256 + lane * 4) = h;
    }
    if (lane == 0) sc4[pos] = make_float4(wts0 * inv, alpha[0], alpha[1], alpha[2]);
  }
}

// ---------------------------------------------------------------------------
extern "C" void kernel_launch(void* const* d_in, const int* in_sizes, int n_in,
                              void* d_out, int out_size, void* d_ws, size_t ws_size,
                              hipStream_t stream) {
  const float* hiddens = (const float*)d_in[0];
  const int* masks = (const int*)d_in[1];
  const int* begins = (const int*)d_in[2];
  const int* blens = (const int*)d_in[3];
  const int* middles = (const int*)d_in[4];
  const int* mlens = (const int*)d_in[5];
  const int* ends = (const int*)d_in[6];
  const int* elens = (const int*)d_in[7];
  const float* emb = (const float*)d_in[8];
  const float* Wh = (const float*)d_in[9];
  const float* bh = (const float*)d_in[10];
  const float* Wb = (const float*)d_in[11];
  const float* bb = (const float*)d_in[12];
  const float* Wm = (const float*)d_in[13];
  const float* bm = (const float*)d_in[14];
  const float* We = (const float*)d_in[15];
  const float* be = (const float*)d_in[16];
  const float* Wg = (const float*)d_in[17];
  const float* bg = (const float*)d_in[18];
  float* out = (float*)d_out;

  char* ws = (char*)d_ws;
  size_t off = 0;
  auto alloc = [&](size_t bytes) -> char* {
    char* p = ws + off;
    off += (bytes + 255) & ~(size_t)255;
    return p;
  };
  u16* Xh = (u16*)alloc((size_t)8192 * 512 * 2);
  u16* Whq = (u16*)alloc((size_t)512 * 512 * 2);
  u16* Acat = (u16*)alloc((size_t)1408 * 512 * 2);   // [Whk | WkT]
  u16* Breg = (u16*)alloc((size_t)1920 * 512 * 2);   // [M | WhvT | Wcomb]
  u16* WvT = (u16*)alloc((size_t)512 * 768 * 2);
  u16* HPb = (u16*)alloc((size_t)8192 * 1408 * 2);   // [hv fp16 | P fp16]
  float* lmr = (float*)alloc((size_t)8192 * 9 * 4);
  float* s0c = (float*)alloc((size_t)8192 * 4);
  float* bcat = (float*)alloc((size_t)1408 * 4);
  float* u = (float*)alloc((size_t)512 * 4);
  float* cbuf = (float*)alloc((size_t)4);
  float* sc4 = (float*)alloc((size_t)8192 * 4 * 4);
  u16* Ebar = (u16*)alloc((size_t)8192 * 768 * 2);
  int* idx = (int*)alloc((size_t)8192 * 4);
  int* perm = (int*)alloc((size_t)8192 * 4);
  int* cnts = (int*)alloc((size_t)256);
  if (off > ws_size) return;  // fail loudly (output stays poisoned)

  // 0) zero partition counters
  hipMemsetAsync(cnts, 0, 8, stream);
  // 1) all preps in one launch (incl. mask partition)
  prep_all<<<1572, 256, 0, stream>>>(hiddens, Wg, bg, Wh, Wb, Wm, We, bb, bm, be,
                                     bh, masks, Xh, lmr, s0c, Breg, Acat, Whq,
                                     WvT, bcat, u, cbuf, idx, perm, cnts);
  // 2) gemmA: Breg[M rows 0..511; Wcomb rows 1024..1919] = Acat @ Whq^T
  gemm_k<1><<<dim3(11, 4), 256, 0, stream>>>(
      Acat, Whq, nullptr, nullptr, nullptr, Breg, 512, nullptr, nullptr,
      nullptr, nullptr, nullptr, nullptr, nullptr, nullptr, nullptr);
  // 3) gemmB: y<4 -> s0 (group0); y4-7 -> hv (all); y>=8 -> P (group1)
  gemm_k<0><<<dim3(64, 15), 256, 0, stream>>>(
      Xh, Breg, u, bcat, nullptr, HPb, 512, Xh, s0c, idx, cnts,
      nullptr, nullptr, nullptr, nullptr, nullptr);
  // 4) fused attention -> sc4 + Ebar
  attn_kernel<<<2048, 256, 0, stream>>>(masks, begins, blens, middles, mlens,
                                        ends, elens, emb, HPb, lmr, s0c, cbuf,
                                        perm, (float4*)sc4, Ebar);
  // 5) gemmC: out = sc4 epilogue + Ebar @ WvT^T  (128x64 tiles, 2 blocks/CU)
  gemm_k<2><<<dim3(64, 8), 256, 0, stream>>>(
      Ebar, WvT, nullptr, nullptr, out, nullptr, 768, nullptr, nullptr,
      nullptr, nullptr, (const float4*)sc4, HPb, bb, bm, be);
}